// Round 8
// baseline (66.336 us; speedup 1.0000x reference)
//
#include <hip/hip_runtime.h>
#include <math.h>

// NoisyTopkRouter: x[T,2048] @ {Wg,Wn}[8,2048]^T -> logits[T,8] each,
// noisy = noise * softplus(noisy_pre) + gate; top-2 -> softmax -> scatter.
// T = 32768, D = 2048, E = 8, k = 2.
//
// R8: TLP x2 again. R6 (2 blocks/CU) -> 82.9 us, R7 (4 blocks/CU) -> 62.2 us.
// Now CH=32 (8 KB chunks, 16 KB LDS/block) and K-split 4 -> 2048 blocks =
// 8 blocks/CU, 32 waves/CU (hardware max). Same validated machinery:
// global_load_lds staging (no staging VGPRs), XOR-pre-swizzled source +
// swizzled ds_read_b128, wave-uniform scalar W, acc[16]/lane (~40 VGPR).
// Runtime ws_size guard falls back to K-split 2 (R7 shape) if scratch tight.

#define RD 2048
#define RE 8
#define NE16 16               // stacked experts: 0..7 = gate, 8..15 = noise
#define TOKB 64               // tokens per block (lane = token)
#define CH 32                 // d's per chunk (8 KB per chunk)
#define NW 4                  // waves per block

#define AS1 __attribute__((address_space(1)))
#define AS3 __attribute__((address_space(3)))

__device__ __forceinline__ void gload_lds16(const float* g, float* l) {
    // HBM -> LDS DMA, 16 B per lane; LDS dest is wave-uniform base + lane*16.
    __builtin_amdgcn_global_load_lds((const AS1 unsigned int*)g,
                                     (AS3 unsigned int*)l, 16, 0, 0);
}

// ---- kernel 1: WT[d][e] = (e<8 ? Wg[e][d] : Wn[e-8][d]) ----
__global__ __launch_bounds__(256) void transpose_w_kernel(
    const float* __restrict__ Wg, const float* __restrict__ Wn,
    float* __restrict__ WT)
{
    const int idx = blockIdx.x * 256 + threadIdx.x;   // 0 .. 2048*16-1
    const int d = idx >> 4;
    const int e = idx & 15;
    WT[idx] = (e < 8) ? Wg[e * RD + d] : Wn[(e - 8) * RD + d];
}

// ---- kernel 2: main GEMV, one K-slice per block, partials to d_ws ----
template <int KSL>
__global__ __launch_bounds__(256) void router_main_kernel(
    const float* __restrict__ x,
    const float* __restrict__ WT,     // [2048][16]
    float* __restrict__ pws,          // [KSL][T][16] partial sums
    int T)
{
    constexpr int KLEN = RD / KSL;    // d's per block
    constexpr int NCH = KLEN / CH;    // chunks per block
    __shared__ float xb[2][TOKB * CH];   // 2 x 8 KB double buffer

    const int tid = threadIdx.x;
    const int w = tid >> 6;              // wave 0..3 -> 8-d sub-range of chunk
    const int l = tid & 63;              // lane = token within tile
    const int NTB = T / TOKB;
    const int bt = blockIdx.x % NTB;     // token tile
    const int kslice = blockIdx.x / NTB; // K-slice
    const int tokBase = bt * TOKB;
    const int kbase = kslice * KLEN;

    float acc[NE16];
#pragma unroll
    for (int e = 0; e < NE16; ++e) acc[e] = 0.f;

    // staging: per chunk 8 x 1 KB DMA insts; inst i = w*2+s covers token
    // rows i*8..i*8+7 (32-float rows, 8 16B-segs each). lane -> row
    // t = i*8 + (l>>3), phys seg p = l&7; source seg XOR-pre-swizzled
    // (p ^ (t&7)) so the consume side can de-swizzle bank-free.
    {
#pragma unroll
        for (int s = 0; s < 2; ++s) {
            const int i = w * 2 + s;
            const int t = i * 8 + (l >> 3);
            const int p = l & 7;
            const float* gsrc = x + (size_t)(tokBase + t) * RD + kbase
                                + ((p ^ (t & 7)) << 2);
            gload_lds16(gsrc, &xb[0][i * 256]);
        }
    }
    __syncthreads();   // drains vmcnt -> chunk 0 resident

#pragma unroll 1
    for (int c = 0; c < NCH; ++c) {
        const int buf = c & 1;

        if (c + 1 < NCH) {
#pragma unroll
            for (int s = 0; s < 2; ++s) {
                const int i = w * 2 + s;
                const int t = i * 8 + (l >> 3);
                const int p = l & 7;
                const float* gsrc = x + (size_t)(tokBase + t) * RD + kbase
                                    + (c + 1) * CH + ((p ^ (t & 7)) << 2);
                gload_lds16(gsrc, &xb[buf ^ 1][i * 256]);
            }
        }

        // consume: wave w covers logical segs q = w*2, w*2+1
        // (d = c*32 + q*4 + ii). W base is wave-uniform -> scalar loads.
        const int wbase = __builtin_amdgcn_readfirstlane(
            (kbase + c * CH + w * 8) * NE16);
        const float* __restrict__ wt = WT + wbase;
#pragma unroll
        for (int r = 0; r < 2; ++r) {
            const int q = w * 2 + r;
            const float4 xq = *reinterpret_cast<const float4*>(
                &xb[buf][l * CH + ((q ^ (l & 7)) << 2)]);
            const float xs[4] = {xq.x, xq.y, xq.z, xq.w};
#pragma unroll
            for (int ii = 0; ii < 4; ++ii) {
                const float* wrow = wt + (r * 4 + ii) * NE16;
#pragma unroll
                for (int e = 0; e < NE16; ++e)
                    acc[e] = fmaf(xs[ii], wrow[e], acc[e]);
            }
        }

        __syncthreads();   // next chunk landed; this chunk's readers done
    }

    // ---- cross-wave reduction overlay (xb flat = 4096 floats, need 4096) ----
    float* red = &xb[0][0];
    {
        const int roff = (w * TOKB + l) * NE16;
        *reinterpret_cast<float4*>(&red[roff + 0])  = make_float4(acc[0], acc[1], acc[2], acc[3]);
        *reinterpret_cast<float4*>(&red[roff + 4])  = make_float4(acc[4], acc[5], acc[6], acc[7]);
        *reinterpret_cast<float4*>(&red[roff + 8])  = make_float4(acc[8], acc[9], acc[10], acc[11]);
        *reinterpret_cast<float4*>(&red[roff + 12]) = make_float4(acc[12], acc[13], acc[14], acc[15]);
    }
    __syncthreads();

    // 256 threads: (token, quad) -> sum 4 wave partials, one float4 out
    {
        const int tok = tid >> 2;
        const int q4 = tid & 3;
        float4 s = make_float4(0.f, 0.f, 0.f, 0.f);
#pragma unroll
        for (int wv = 0; wv < NW; ++wv) {
            const float4 a = *reinterpret_cast<const float4*>(
                &red[(wv * TOKB + tok) * NE16 + q4 * 4]);
            s.x += a.x; s.y += a.y; s.z += a.z; s.w += a.w;
        }
        float* dst = pws + ((size_t)kslice * T + tokBase + tok) * NE16 + q4 * 4;
        *reinterpret_cast<float4*>(dst) = s;
    }
}

// ---- kernel 3: combine K-slices + epilogue ----
__global__ __launch_bounds__(256) void router_finalize_kernel(
    const float* __restrict__ pws,
    const float* __restrict__ bg,
    const float* __restrict__ bn,
    const float* __restrict__ noise,
    float* __restrict__ out_router,
    float* __restrict__ out_experts,
    int T, int ksl)
{
    const int tok = blockIdx.x * 256 + threadIdx.x;

    float g[RE], nn[RE];
#pragma unroll
    for (int e = 0; e < RE; ++e) { g[e] = bg[e]; nn[e] = bn[e]; }
#pragma unroll 1
    for (int s = 0; s < ksl; ++s) {
        const float* p = pws + ((size_t)s * T + tok) * NE16;
#pragma unroll
        for (int e = 0; e < RE; ++e) { g[e] += p[e]; nn[e] += p[8 + e]; }
    }

    const float4* nzp = reinterpret_cast<const float4*>(noise + (size_t)tok * RE);
    const float4 nz0 = nzp[0];
    const float4 nz1 = nzp[1];
    const float nzv[RE] = {nz0.x, nz0.y, nz0.z, nz0.w,
                           nz1.x, nz1.y, nz1.z, nz1.w};

    float v[RE];
#pragma unroll
    for (int e = 0; e < RE; ++e) {
        const float p = nn[e];
        // stable softplus: max(p,0) + log1p(exp(-|p|))
        const float sp = fmaxf(p, 0.f) + log1pf(expf(-fabsf(p)));
        v[e] = fmaf(nzv[e], sp, g[e]);
    }

    // top-2 of 8; strict '>' keeps the lowest index on ties, matching
    // jax.lax.top_k / torch.topk ordering.
    int i1 = 0; float m1 = v[0];
#pragma unroll
    for (int e = 1; e < RE; ++e)
        if (v[e] > m1) { m1 = v[e]; i1 = e; }
    int i2 = -1; float m2 = -INFINITY;
#pragma unroll
    for (int e = 0; e < RE; ++e)
        if (e != i1 && v[e] > m2) { m2 = v[e]; i2 = e; }

    const float e2 = expf(m2 - m1);
    const float inv = 1.f / (1.f + e2);
    const float p1s = inv;
    const float p2s = e2 * inv;

    float r[RE];
#pragma unroll
    for (int e = 0; e < RE; ++e)
        r[e] = (e == i1) ? p1s : ((e == i2) ? p2s : 0.f);

    float4* orow = reinterpret_cast<float4*>(out_router + (size_t)tok * RE);
    orow[0] = make_float4(r[0], r[1], r[2], r[3]);
    orow[1] = make_float4(r[4], r[5], r[6], r[7]);

    float2* erow = reinterpret_cast<float2*>(out_experts + (size_t)tok * 2);
    *erow = make_float2((float)i1, (float)i2);
}

extern "C" void kernel_launch(void* const* d_in, const int* in_sizes, int n_in,
                              void* d_out, int out_size, void* d_ws, size_t ws_size,
                              hipStream_t stream) {
    const float* x   = (const float*)d_in[0];
    const float* Wg  = (const float*)d_in[1];
    const float* bg  = (const float*)d_in[2];
    const float* Wn  = (const float*)d_in[3];
    const float* bn  = (const float*)d_in[4];
    const float* nz  = (const float*)d_in[5];
    const int T = in_sizes[0] / RD;              // 32768

    float* WT  = (float*)d_ws;                   // 128 KB
    float* pws = WT + (size_t)RD * NE16;         // KSL*T*16 floats

    float* out_router  = (float*)d_out;                // T*8 floats
    float* out_experts = out_router + (size_t)T * RE;  // T*2 floats (as f32)

    hipLaunchKernelGGL(transpose_w_kernel, dim3((RD * NE16) / 256), dim3(256),
                       0, stream, Wg, Wn, WT);

    const int NTB = T / TOKB;                    // 512
    const size_t need4 = (size_t)RD * NE16 * 4 + (size_t)4 * T * NE16 * 4;
    if (ws_size >= need4) {
        hipLaunchKernelGGL(router_main_kernel<4>, dim3(NTB * 4), dim3(256), 0,
                           stream, x, WT, pws, T);
        hipLaunchKernelGGL(router_finalize_kernel, dim3(T / 256), dim3(256), 0,
                           stream, pws, bg, bn, nz, out_router, out_experts,
                           T, 4);
    } else {
        hipLaunchKernelGGL(router_main_kernel<2>, dim3(NTB * 2), dim3(256), 0,
                           stream, x, WT, pws, T);
        hipLaunchKernelGGL(router_finalize_kernel, dim3(T / 256), dim3(256), 0,
                           stream, pws, bg, bn, nz, out_router, out_experts,
                           T, 2);
    }
}

// Round 9
// 60.770 us; speedup vs baseline: 1.0916x; 1.0916x over previous
//
#include <hip/hip_runtime.h>
#include <math.h>

// NoisyTopkRouter: x[T,2048] @ {Wg,Wn}[8,2048]^T -> logits[T,8] each,
// noisy = noise * softplus(noisy_pre) + gate; top-2 -> softmax -> scatter.
// T = 32768, D = 2048, E = 8, k = 2.
//
// R9: counted-vmcnt pipeline (T3/T4) on the R7 shape. __syncthreads()'s
// implicit vmcnt(0) drain made every chunk pay full HBM latency; now a
// 4-deep LDS ring with raw s_barrier + s_waitcnt vmcnt(4) keeps 2 chunks
// of DMA permanently in flight (never drains in the main loop).
// Carried over unchanged (validated R6-R8): global_load_lds staging,
// XOR-pre-swizzled source + swizzled ds_read_b128, wave-uniform scalar W,
// acc[16]/lane, K-split 2 + finalize kernel.

#define RD 2048
#define RE 8
#define NE16 16               // stacked experts: 0..7 = gate, 8..15 = noise
#define TOKB 64               // tokens per block (lane = token)
#define CH 32                 // d's per chunk (8 KB per chunk)
#define KSL 2                 // K-slices (blocks per token tile)
#define KLEN (RD / KSL)       // 1024 d's per block
#define NCH (KLEN / CH)       // 32 chunks
#define NW 4                  // waves per block
#define DEPTH 4               // LDS ring depth

#define AS1 __attribute__((address_space(1)))
#define AS3 __attribute__((address_space(3)))

#define WAITVM(N) asm volatile("s_waitcnt vmcnt(" #N ")" ::: "memory")

__device__ __forceinline__ void gload_lds16(const float* g, float* l) {
    // HBM -> LDS DMA, 16 B per lane; LDS dest is wave-uniform base + lane*16.
    __builtin_amdgcn_global_load_lds((const AS1 unsigned int*)g,
                                     (AS3 unsigned int*)l, 16, 0, 0);
}

// ---- kernel 1: WT[d][e] = (e<8 ? Wg[e][d] : Wn[e-8][d]) ----
__global__ __launch_bounds__(256) void transpose_w_kernel(
    const float* __restrict__ Wg, const float* __restrict__ Wn,
    float* __restrict__ WT)
{
    const int idx = blockIdx.x * 256 + threadIdx.x;   // 0 .. 2048*16-1
    const int d = idx >> 4;
    const int e = idx & 15;
    WT[idx] = (e < 8) ? Wg[e * RD + d] : Wn[(e - 8) * RD + d];
}

// ---- kernel 2: main GEMV, one K-slice per block, partials to d_ws ----
__global__ __launch_bounds__(256) void router_main_kernel(
    const float* __restrict__ x,
    const float* __restrict__ WT,     // [2048][16]
    float* __restrict__ pws,          // [KSL][T][16] partial sums
    int T)
{
    __shared__ float xb[DEPTH][TOKB * CH];   // 4 x 8 KB ring

    const int tid = threadIdx.x;
    const int w = tid >> 6;              // wave 0..3 -> 8-d sub-range of chunk
    const int l = tid & 63;              // lane = token within tile
    const int NTB = T / TOKB;
    const int bt = blockIdx.x % NTB;     // token tile
    const int kslice = blockIdx.x / NTB; // K-slice
    const int tokBase = bt * TOKB;
    const int kbase = kslice * KLEN;

    float acc[NE16];
#pragma unroll
    for (int e = 0; e < NE16; ++e) acc[e] = 0.f;

    // Staging geometry (per chunk): 8 x 1 KB DMA insts; inst i = w*2+s
    // covers token rows i*8 .. i*8+7 (32-float rows, 8 16B-segs each).
    // lane -> row t = i*8 + (l>>3)  (so t&7 == l>>3), phys seg p = l&7;
    // the GLOBAL source seg is XOR-pre-swizzled (p ^ (t&7)) so the consume
    // side's swizzled read is bank-free while the LDS dest stays linear.
    const size_t laneoff = (size_t)(l >> 3) * RD + ((((l & 7) ^ (l >> 3))) << 2);
    const float* p0 = x + (size_t)(tokBase + (w * 2 + 0) * 8) * RD + kbase + laneoff;
    const float* p1 = x + (size_t)(tokBase + (w * 2 + 1) * 8) * RD + kbase + laneoff;
    float* d0base = &xb[0][(w * 2 + 0) * 256];
    float* d1base = &xb[0][(w * 2 + 1) * 256];

    // prologue: stage chunks 0 and 1 (4 insts outstanding per wave)
    gload_lds16(p0 + 0 * CH, d0base + 0 * (TOKB * CH));
    gload_lds16(p1 + 0 * CH, d1base + 0 * (TOKB * CH));
    gload_lds16(p0 + 1 * CH, d0base + 1 * (TOKB * CH));
    gload_lds16(p1 + 1 * CH, d1base + 1 * (TOKB * CH));

#pragma unroll 1
    for (int c = 0; c < NCH; ++c) {
        const int b = c & (DEPTH - 1);

        if (c + 2 < NCH) {
            const int nb = (c + 2) & (DEPTH - 1);
            gload_lds16(p0 + (c + 2) * CH, d0base + nb * (TOKB * CH));
            gload_lds16(p1 + (c + 2) * CH, d1base + nb * (TOKB * CH));
            WAITVM(4);               // chunk c's 2 insts retired; c+1,c+2 fly
        } else if (c + 2 == NCH) {
            WAITVM(2);               // chunk c retired; c+1 still in flight
        } else {
            WAITVM(0);               // last chunk
        }
        __builtin_amdgcn_s_barrier();       // all waves' chunk-c DMA landed;
        __builtin_amdgcn_sched_barrier(0);  // and pin: no hoisting across

        // consume chunk c: wave w covers logical segs q = w*2, w*2+1
        // (d = c*32 + q*4 + ii). W base wave-uniform -> scalar loads.
        const int wbase = __builtin_amdgcn_readfirstlane(
            (kbase + c * CH + w * 8) * NE16);
        const float* __restrict__ wt = WT + wbase;
#pragma unroll
        for (int r = 0; r < 2; ++r) {
            const int q = w * 2 + r;
            const float4 xq = *reinterpret_cast<const float4*>(
                &xb[b][l * CH + ((q ^ (l & 7)) << 2)]);
            const float xs[4] = {xq.x, xq.y, xq.z, xq.w};
#pragma unroll
            for (int ii = 0; ii < 4; ++ii) {
                const float* wrow = wt + (r * 4 + ii) * NE16;
#pragma unroll
                for (int e = 0; e < NE16; ++e)
                    acc[e] = fmaf(xs[ii], wrow[e], acc[e]);
            }
        }
        // NOTE: ring depth 4 + per-iter barrier separates stage(c+2)'s
        // overwrite (buf (c+2)%4, last held chunk c-2) from all waves'
        // reads of chunk c-2 (finished before barrier c-1). No 2nd barrier.
    }

    __syncthreads();   // everything retired; safe to overlay xb

    // ---- cross-wave reduction overlay (xb flat = 8192 floats, need 4096) ----
    float* red = &xb[0][0];
    {
        const int roff = (w * TOKB + l) * NE16;
        *reinterpret_cast<float4*>(&red[roff + 0])  = make_float4(acc[0], acc[1], acc[2], acc[3]);
        *reinterpret_cast<float4*>(&red[roff + 4])  = make_float4(acc[4], acc[5], acc[6], acc[7]);
        *reinterpret_cast<float4*>(&red[roff + 8])  = make_float4(acc[8], acc[9], acc[10], acc[11]);
        *reinterpret_cast<float4*>(&red[roff + 12]) = make_float4(acc[12], acc[13], acc[14], acc[15]);
    }
    __syncthreads();

    // 256 threads: (token, quad) -> sum 4 wave partials, one float4 out
    {
        const int tok = tid >> 2;
        const int q4 = tid & 3;
        float4 s = make_float4(0.f, 0.f, 0.f, 0.f);
#pragma unroll
        for (int wv = 0; wv < NW; ++wv) {
            const float4 a = *reinterpret_cast<const float4*>(
                &red[(wv * TOKB + tok) * NE16 + q4 * 4]);
            s.x += a.x; s.y += a.y; s.z += a.z; s.w += a.w;
        }
        float* dst = pws + ((size_t)kslice * T + tokBase + tok) * NE16 + q4 * 4;
        *reinterpret_cast<float4*>(dst) = s;
    }
}

// ---- kernel 3: combine K-slices + epilogue ----
__global__ __launch_bounds__(256) void router_finalize_kernel(
    const float* __restrict__ pws,
    const float* __restrict__ bg,
    const float* __restrict__ bn,
    const float* __restrict__ noise,
    float* __restrict__ out_router,
    float* __restrict__ out_experts,
    int T)
{
    const int tok = blockIdx.x * 256 + threadIdx.x;

    const float* pp0 = pws + (size_t)tok * NE16;
    const float* pp1 = pws + ((size_t)T + tok) * NE16;

    float g[RE], nn[RE];
#pragma unroll
    for (int e = 0; e < RE; ++e) {
        g[e]  = pp0[e] + pp1[e] + bg[e];
        nn[e] = pp0[8 + e] + pp1[8 + e] + bn[e];
    }

    const float4* nzp = reinterpret_cast<const float4*>(noise + (size_t)tok * RE);
    const float4 nz0 = nzp[0];
    const float4 nz1 = nzp[1];
    const float nzv[RE] = {nz0.x, nz0.y, nz0.z, nz0.w,
                           nz1.x, nz1.y, nz1.z, nz1.w};

    float v[RE];
#pragma unroll
    for (int e = 0; e < RE; ++e) {
        const float p = nn[e];
        // stable softplus: max(p,0) + log1p(exp(-|p|))
        const float sp = fmaxf(p, 0.f) + log1pf(expf(-fabsf(p)));
        v[e] = fmaf(nzv[e], sp, g[e]);
    }

    // top-2 of 8; strict '>' keeps the lowest index on ties, matching
    // jax.lax.top_k / torch.topk ordering.
    int i1 = 0; float m1 = v[0];
#pragma unroll
    for (int e = 1; e < RE; ++e)
        if (v[e] > m1) { m1 = v[e]; i1 = e; }
    int i2 = -1; float m2 = -INFINITY;
#pragma unroll
    for (int e = 0; e < RE; ++e)
        if (e != i1 && v[e] > m2) { m2 = v[e]; i2 = e; }

    const float e2 = expf(m2 - m1);
    const float inv = 1.f / (1.f + e2);
    const float p1s = inv;
    const float p2s = e2 * inv;

    float r[RE];
#pragma unroll
    for (int e = 0; e < RE; ++e)
        r[e] = (e == i1) ? p1s : ((e == i2) ? p2s : 0.f);

    float4* orow = reinterpret_cast<float4*>(out_router + (size_t)tok * RE);
    orow[0] = make_float4(r[0], r[1], r[2], r[3]);
    orow[1] = make_float4(r[4], r[5], r[6], r[7]);

    float2* erow = reinterpret_cast<float2*>(out_experts + (size_t)tok * 2);
    *erow = make_float2((float)i1, (float)i2);
}

extern "C" void kernel_launch(void* const* d_in, const int* in_sizes, int n_in,
                              void* d_out, int out_size, void* d_ws, size_t ws_size,
                              hipStream_t stream) {
    const float* x   = (const float*)d_in[0];
    const float* Wg  = (const float*)d_in[1];
    const float* bg  = (const float*)d_in[2];
    const float* Wn  = (const float*)d_in[3];
    const float* bn  = (const float*)d_in[4];
    const float* nz  = (const float*)d_in[5];
    const int T = in_sizes[0] / RD;              // 32768

    float* WT  = (float*)d_ws;                   // 128 KB
    float* pws = WT + (size_t)RD * NE16;         // KSL*T*16 floats = 4 MB

    float* out_router  = (float*)d_out;                // T*8 floats
    float* out_experts = out_router + (size_t)T * RE;  // T*2 floats (as f32)

    hipLaunchKernelGGL(transpose_w_kernel, dim3((RD * NE16) / 256), dim3(256),
                       0, stream, Wg, Wn, WT);

    const int NTB = T / TOKB;                    // 512
    hipLaunchKernelGGL(router_main_kernel, dim3(NTB * KSL), dim3(256), 0,
                       stream, x, WT, pws, T);

    hipLaunchKernelGGL(router_finalize_kernel, dim3(T / 256), dim3(256), 0,
                       stream, pws, bg, bn, nz, out_router, out_experts, T);
}